// Round 6
// baseline (330.349 us; speedup 1.0000x reference)
//
#include <hip/hip_runtime.h>
#include <hip/hip_bf16.h>

typedef __bf16 bf16x8 __attribute__((ext_vector_type(8)));
typedef unsigned short u16x8 __attribute__((ext_vector_type(8)));
typedef float f32x4 __attribute__((ext_vector_type(4)));
typedef __hip_bfloat16 hbf;

static constexpr int B = 4, T = 512, D = 1024, N = 16, H = 256;
static constexpr size_t E_ELEMS = (size_t)B * N * T * D;    // 33,554,432
static constexpr size_t ATTN_ELEMS = (size_t)B * N * T * T; // 16,777,216

__device__ __forceinline__ bf16x8 load8(const hbf* p) {
  return *reinterpret_cast<const bf16x8*>(p);
}

__device__ __forceinline__ unsigned short f2bf(float f) {
  union { __hip_bfloat16 h; unsigned short u; } cv;
  cv.h = __float2bfloat16(f);
  return cv.u;
}

// async global->LDS, 16B per lane; lds dest must be waveBase + lane*16
__device__ __forceinline__ void gload16(const hbf* g, hbf* l) {
  __builtin_amdgcn_global_load_lds(
      (const __attribute__((address_space(1))) void*)g,
      (__attribute__((address_space(3))) void*)l, 16, 0, 0);
}

// T1: bijective XCD swizzle (8 XCDs, nwg % 8 == 0). Blocks i with equal i%8
// land on one XCD; this remap makes each XCD own a CONTIGUOUS logical range,
// so logical neighbors (which share operand panels) share an L2.
template <int NWG>
__device__ __forceinline__ int xcd_swizzle(int i) {
  return (i & 7) * (NWG / 8) + (i >> 3);
}

// ---------------- fp32 -> bf16 row-major cast (8 elems / thread) -------------
__global__ __launch_bounds__(256) void cast_bf_k(const float* __restrict__ in,
                                                 unsigned short* __restrict__ out,
                                                 int n8) {
  int i = blockIdx.x * 256 + threadIdx.x;
  if (i >= n8) return;
  const float4* p = reinterpret_cast<const float4*>(in) + (size_t)i * 2;
  float4 a = p[0], b = p[1];
  u16x8 v;
  v[0] = f2bf(a.x); v[1] = f2bf(a.y); v[2] = f2bf(a.z); v[3] = f2bf(a.w);
  v[4] = f2bf(b.x); v[5] = f2bf(b.y); v[6] = f2bf(b.z); v[7] = f2bf(b.w);
  reinterpret_cast<u16x8*>(out)[i] = v;
}

// ------------- batched transpose+cast: in[z][r][c] fp32 -> out[z][c][r] bf16 -
__global__ void transpose_cast_k(const float* __restrict__ in,
                                 unsigned short* __restrict__ out, int R, int C) {
  __shared__ unsigned short tile[32][33];
  int z = blockIdx.z;
  int c0 = blockIdx.x * 32, r0 = blockIdx.y * 32;
  const float* inz = in + (size_t)z * R * C;
  unsigned short* outz = out + (size_t)z * R * C;
  int tx = threadIdx.x, ty = threadIdx.y;
  for (int i = ty; i < 32; i += 8)
    tile[i][tx] = f2bf(inz[(size_t)(r0 + i) * C + (c0 + tx)]);
  __syncthreads();
  for (int i = ty; i < 32; i += 8)
    outz[(size_t)(c0 + i) * R + (r0 + tx)] = tile[tx][i];
}

// =========== stage A: wq[b][n][t][h] = sum_d x[b][t][d] * w[n][d][h] =========
// 128x64x(BK=32) LDS-tiled, 2-phase dbuf, 1024 blocks (4/CU). (unchanged R5)
__global__ __launch_bounds__(256) void gemm_wq_tiled(const hbf* __restrict__ xb,
                                                     const hbf* __restrict__ wT,
                                                     hbf* __restrict__ wq) {
  __shared__ __align__(16) hbf As[2][128 * 32];
  __shared__ __align__(16) hbf Bs[2][64 * 32];
  int idx = xcd_swizzle<1024>(blockIdx.x);  // b*256 + mt*64 + jt
  int b = idx >> 8, mt = (idx >> 6) & 3, jt = idx & 63;
  const hbf* A = xb + (size_t)b * T * D + (size_t)mt * 128 * D;
  const hbf* Bp = wT + (size_t)jt * 64 * D;
  int tid = threadIdx.x, wave = tid >> 6, lane = tid & 63;
  int col = lane & 15, quad = lane >> 4;
  int wm = wave & 1, wn = wave >> 1;

  auto STAGE = [&](int k0, int bi) {
    if (wave < 2) {
#pragma unroll
      for (int j = 0; j < 4; ++j) {
        int slot = (wave * 4 + j) * 64 + lane;
        int row = slot >> 2, kc = slot & 3;
        gload16(A + (size_t)row * D + k0 + kc * 8, As[bi] + slot * 8);
      }
    } else {
#pragma unroll
      for (int j = 0; j < 2; ++j) {
        int slot = ((wave - 2) * 2 + j) * 64 + lane;
        int row = slot >> 2, kc = slot & 3;
        gload16(Bp + (size_t)row * D + k0 + kc * 8, Bs[bi] + slot * 8);
      }
    }
  };

  f32x4 acc[4][2] = {};
  STAGE(0, 0);
  int cur = 0;
  for (int k0 = 0; k0 < D; k0 += 32, cur ^= 1) {
    __syncthreads();
    if (k0 + 32 < D) STAGE(k0 + 32, cur ^ 1);
    bf16x8 a[4], bb[2];
#pragma unroll
    for (int s = 0; s < 4; ++s)
      a[s] = load8(As[cur] + (wm * 64 + s * 16 + col) * 32 + quad * 8);
#pragma unroll
    for (int t = 0; t < 2; ++t)
      bb[t] = load8(Bs[cur] + (wn * 32 + t * 16 + col) * 32 + quad * 8);
#pragma unroll
    for (int s = 0; s < 4; ++s)
#pragma unroll
      for (int t = 0; t < 2; ++t)
        acc[s][t] = __builtin_amdgcn_mfma_f32_16x16x32_bf16(a[s], bb[t], acc[s][t], 0, 0, 0);
  }
  hbf* wqb = wq + (size_t)b * 16 * T * H;
#pragma unroll
  for (int s = 0; s < 4; ++s) {
    int row = mt * 128 + wm * 64 + s * 16 + quad * 4;
#pragma unroll
    for (int t = 0; t < 2; ++t) {
      int j = jt * 64 + wn * 32 + t * 16 + col;
      int n = j >> 8, h = j & 255;
      hbf* dst = wqb + (size_t)n * T * H + (size_t)row * H + h;
#pragma unroll
      for (int r = 0; r < 4; ++r)
        dst[(size_t)r * H] = __float2bfloat16(acc[s][t][r]);
    }
  }
}

// ------- stage B: 32 rows/block (1024 blocks), staged B-panel, in-reg softmax
// (unchanged R5)
__global__ __launch_bounds__(256) void attn_k(const hbf* __restrict__ wq,
                                              float* __restrict__ attn_f,
                                              hbf* __restrict__ attn_b) {
  __shared__ __align__(16) hbf Bs[2][512 * 32];  // 64 KB
  __shared__ float redA[4][32];
  __shared__ float redB[4][32];
  int blk = xcd_swizzle<1024>(blockIdx.x);  // bn*16 + mt
  int bn = blk >> 4, mt = blk & 15;
  int m0 = mt * 32;
  const hbf* Wq = wq + (size_t)bn * T * H;
  int wave = threadIdx.x >> 6, lane = threadIdx.x & 63;
  int col = lane & 15, quad = lane >> 4;

  auto STAGE = [&](int k0, int bi) {
    hbf* Bl = Bs[bi];
#pragma unroll
    for (int j = 0; j < 8; ++j) {
      int slot = (wave * 8 + j) * 64 + lane;
      int row = slot >> 2, kc = slot & 3;
      gload16(Wq + (size_t)row * H + k0 + kc * 8, Bl + slot * 8);
    }
  };

  f32x4 acc[2][8] = {};
  STAGE(0, 0);
  int cur = 0;
  for (int k0 = 0; k0 < H; k0 += 32, cur ^= 1) {
    __syncthreads();
    if (k0 + 32 < H) STAGE(k0 + 32, cur ^ 1);
    bf16x8 a[2];
#pragma unroll
    for (int s = 0; s < 2; ++s)
      a[s] = load8(Bs[cur] + (m0 + s * 16 + col) * 32 + quad * 8);
#pragma unroll
    for (int t = 0; t < 8; ++t) {
      bf16x8 bfr = load8(Bs[cur] + (wave * 128 + t * 16 + col) * 32 + quad * 8);
#pragma unroll
      for (int s = 0; s < 2; ++s)
        acc[s][t] = __builtin_amdgcn_mfma_f32_16x16x32_bf16(a[s], bfr, acc[s][t], 0, 0, 0);
    }
  }

  float mrow[2][4], inv[2][4];
#pragma unroll
  for (int s = 0; s < 2; ++s)
#pragma unroll
    for (int r = 0; r < 4; ++r) {
      float pm = acc[s][0][r];
#pragma unroll
      for (int t = 1; t < 8; ++t) pm = fmaxf(pm, acc[s][t][r]);
#pragma unroll
      for (int off = 8; off >= 1; off >>= 1) pm = fmaxf(pm, __shfl_xor(pm, off));
      if (col == 0) redA[wave][s * 16 + quad * 4 + r] = pm;
    }
  __syncthreads();
#pragma unroll
  for (int s = 0; s < 2; ++s)
#pragma unroll
    for (int r = 0; r < 4; ++r) {
      int rl = s * 16 + quad * 4 + r;
      mrow[s][r] = fmaxf(fmaxf(redA[0][rl], redA[1][rl]),
                         fmaxf(redA[2][rl], redA[3][rl]));
      float sm = 0.f;
#pragma unroll
      for (int t = 0; t < 8; ++t) {
        float e = __expf(acc[s][t][r] - mrow[s][r]);
        acc[s][t][r] = e;
        sm += e;
      }
#pragma unroll
      for (int off = 8; off >= 1; off >>= 1) sm += __shfl_xor(sm, off);
      if (col == 0) redB[wave][rl] = sm;
    }
  __syncthreads();
#pragma unroll
  for (int s = 0; s < 2; ++s)
#pragma unroll
    for (int r = 0; r < 4; ++r) {
      int rl = s * 16 + quad * 4 + r;
      inv[s][r] = 1.0f / (redB[0][rl] + redB[1][rl] + redB[2][rl] + redB[3][rl]);
    }
#pragma unroll
  for (int s = 0; s < 2; ++s)
#pragma unroll
    for (int r = 0; r < 4; ++r) {
      int rl = s * 16 + quad * 4 + r;
      float iv = inv[s][r];
      size_t base = ((size_t)bn * T + m0 + rl) * T;
      float* dst = attn_f + base;
      hbf* dstb = attn_b + base;
#pragma unroll
      for (int t = 0; t < 8; ++t) {
        int c = wave * 128 + t * 16 + col;
        float p = acc[s][t][r] * iv;
        dst[c] = p;
        dstb[c] = __float2bfloat16(p);
      }
    }
}

// ====== stage C v2: 256x256 tile, BK=32, 8 waves, 3-buf counted-vmcnt =======
// 4 phases per K-step; per phase: [q0: vmcnt(4)] -> s_barrier -> stage one
// half-tile (for K-step k+2, buf (k+2)%3) -> ds_read quadrant frags ->
// setprio(1) -> 8 MFMA -> setprio(0). vmcnt never drains to 0 except the
// last step (T4). LDS k-slices XOR-swizzled (T2, rule #21: linear LDS dest,
// inverse-swizzled GLOBAL source, same XOR on read) -> 8-way conflict -> 2-way.
// WAR safety: buf (k+2)%3 last read at step k-1; stage issues are behind
// >=1 barrier after those reads, and async writes cannot land before issue.
__global__ __launch_bounds__(512, 2) void gemm_out_8p(const hbf* __restrict__ attn,
                                                      const hbf* __restrict__ xT,
                                                      float* __restrict__ eout) {
  __shared__ __align__(16) hbf Ab[3][256 * 32];  // 48 KB
  __shared__ __align__(16) hbf Bb[3][256 * 32];  // 48 KB
  int idx = xcd_swizzle<512>(blockIdx.x);   // bn*8 + mt*4 + nt
  int bn = idx >> 3, mt = (idx >> 2) & 1, nt = idx & 3;
  int b = bn >> 4;
  const hbf* Ag = attn + (size_t)bn * T * T + (size_t)(mt * 256) * T;
  const hbf* Bg = xT + (size_t)b * D * T + (size_t)(nt * 256) * T;
  int tid = threadIdx.x;
  int wave = tid >> 6, lane = tid & 63;
  int c = lane & 15, quad = lane >> 4;
  int wm = wave >> 2, wn = wave & 3;          // 2 x 4 wave grid, 128x64 each
  int trow = tid >> 2, tks = tid & 3;         // staging decomposition

  // swizzled read offset (elements): row*32 + (ks ^ ((row>>1)&3))*8
  auto SWZ = [&](int row, int ks) { return row * 32 + ((ks ^ ((row >> 1) & 3)) << 3); };

  // stage one half-tile (8 KB, 1 gload16/thread): q 0/1 = A halves, 2/3 = B
  auto STAGE1 = [&](int kt, int q, int bt) {
    int half = q & 1;
    int row = half * 128 + trow;
    int kse = (tks ^ ((row >> 1) & 3)) << 3;  // inverse-swizzled source slice
    if (q < 2)
      gload16(Ag + (size_t)row * T + kt * 32 + kse, Ab[bt] + half * 4096 + tid * 8);
    else
      gload16(Bg + (size_t)row * T + kt * 32 + kse, Bb[bt] + half * 4096 + tid * 8);
  };

  f32x4 acc[8][4] = {};
  // prologue: K-steps 0 -> buf0, 1 -> buf1 (order matters for vmcnt counts)
#pragma unroll
  for (int q = 0; q < 4; ++q) STAGE1(0, q, 0);
#pragma unroll
  for (int q = 0; q < 4; ++q) STAGE1(1, q, 1);

  constexpr int NK = T / 32;  // 16
  int cb = 0, st = 2;
  bf16x8 a8[8], b4[4];
  for (int k = 0; k < NK; ++k) {
    bool pf = (k + 2 < NK);
    // ---- phase q0: confirm this K-step's tiles; quadrant (m0-3 x n0-1) ----
    if (k == NK - 1)
      asm volatile("s_waitcnt vmcnt(0)" ::: "memory");
    else
      asm volatile("s_waitcnt vmcnt(4)" ::: "memory");
    __builtin_amdgcn_s_barrier();
    if (pf) STAGE1(k + 2, 0, st);
#pragma unroll
    for (int i = 0; i < 4; ++i) a8[i] = load8(Ab[cb] + SWZ(wm * 128 + i * 16 + c, quad));
#pragma unroll
    for (int j = 0; j < 2; ++j) b4[j] = load8(Bb[cb] + SWZ(wn * 64 + j * 16 + c, quad));
    __builtin_amdgcn_s_setprio(1);
#pragma unroll
    for (int i = 0; i < 4; ++i)
#pragma unroll
      for (int j = 0; j < 2; ++j)
        acc[i][j] = __builtin_amdgcn_mfma_f32_16x16x32_bf16(a8[i], b4[j], acc[i][j], 0, 0, 0);
    __builtin_amdgcn_s_setprio(0);
    // ---- phase q1: quadrant (m4-7 x n0-1) ----
    __builtin_amdgcn_s_barrier();
    if (pf) STAGE1(k + 2, 1, st);
#pragma unroll
    for (int i = 4; i < 8; ++i) a8[i] = load8(Ab[cb] + SWZ(wm * 128 + i * 16 + c, quad));
    __builtin_amdgcn_s_setprio(1);
#pragma unroll
    for (int i = 4; i < 8; ++i)
#pragma unroll
      for (int j = 0; j < 2; ++j)
        acc[i][j] = __builtin_amdgcn_mfma_f32_16x16x32_bf16(a8[i], b4[j], acc[i][j], 0, 0, 0);
    __builtin_amdgcn_s_setprio(0);
    // ---- phase q2: quadrant (m0-3 x n2-3) ----
    __builtin_amdgcn_s_barrier();
    if (pf) STAGE1(k + 2, 2, st);
#pragma unroll
    for (int j = 2; j < 4; ++j) b4[j] = load8(Bb[cb] + SWZ(wn * 64 + j * 16 + c, quad));
    __builtin_amdgcn_s_setprio(1);
#pragma unroll
    for (int i = 0; i < 4; ++i)
#pragma unroll
      for (int j = 2; j < 4; ++j)
        acc[i][j] = __builtin_amdgcn_mfma_f32_16x16x32_bf16(a8[i], b4[j], acc[i][j], 0, 0, 0);
    __builtin_amdgcn_s_setprio(0);
    // ---- phase q3: quadrant (m4-7 x n2-3) ----
    __builtin_amdgcn_s_barrier();
    if (pf) STAGE1(k + 2, 3, st);
    __builtin_amdgcn_s_setprio(1);
#pragma unroll
    for (int i = 4; i < 8; ++i)
#pragma unroll
      for (int j = 2; j < 4; ++j)
        acc[i][j] = __builtin_amdgcn_mfma_f32_16x16x32_bf16(a8[i], b4[j], acc[i][j], 0, 0, 0);
    __builtin_amdgcn_s_setprio(0);
    cb = (cb == 2) ? 0 : cb + 1;
    st = (st == 2) ? 0 : st + 1;
  }

  float* Cc = eout + (size_t)bn * T * D;
#pragma unroll
  for (int i = 0; i < 8; ++i) {
    int grow = mt * 256 + wm * 128 + i * 16 + quad * 4;
#pragma unroll
    for (int j = 0; j < 4; ++j) {
      int gcol = nt * 256 + wn * 64 + j * 16 + c;
      float* dst = Cc + (size_t)grow * D + gcol;
#pragma unroll
      for (int r = 0; r < 4; ++r)
        dst[(size_t)r * D] = acc[i][j][r];
    }
  }
}

extern "C" void kernel_launch(void* const* d_in, const int* in_sizes, int n_in,
                              void* d_out, int out_size, void* d_ws, size_t ws_size,
                              hipStream_t stream) {
  const float* x = (const float*)d_in[0];     // [B,T,D] fp32
  const float* w_qs = (const float*)d_in[1];  // [N,D,H] fp32 (w_ks unused per source bug)
  float* e_out = (float*)d_out;               // [B,N,T,D] fp32
  float* attn_out = e_out + E_ELEMS;          // [B,N,T,T] fp32

  char* ws = (char*)d_ws;
  hbf* x_bf = (hbf*)ws;                          // [B,T,D]   4 MB
  hbf* xT   = (hbf*)(ws + (4u << 20));           // [B,D,T]   4 MB
  hbf* wT   = (hbf*)(ws + (8u << 20));           // [N,H,D]   8 MB
  hbf* wq   = (hbf*)(ws + (16u << 20));          // [B*N,T,H] 16 MB
  hbf* attn_b = (hbf*)(ws + (32u << 20));        // [B*N,T,T] 32 MB

  dim3 tb(32, 8);
  cast_bf_k<<<1024, 256, 0, stream>>>(x, (unsigned short*)x_bf, (B * T * D) / 8);
  transpose_cast_k<<<dim3(H / 32, D / 32, N), tb, 0, stream>>>(
      w_qs, (unsigned short*)wT, D, H);
  transpose_cast_k<<<dim3(D / 32, T / 32, B), tb, 0, stream>>>(
      x, (unsigned short*)xT, T, D);
  gemm_wq_tiled<<<1024, 256, 0, stream>>>(x_bf, wT, wq);
  attn_k<<<1024, 256, 0, stream>>>(wq, attn_out, attn_b);
  gemm_out_8p<<<512, 512, 0, stream>>>(attn_b, xT, e_out);
}